// Round 11
// baseline (1212.052 us; speedup 1.0000x reference)
//
#include <hip/hip_runtime.h>

typedef unsigned short u16;
typedef unsigned int u32;

#define N_ATOMS 100000
#define N_BONDS 200000
#define N_EDGES 100000
#define HIDDEN 300
#define HP 320
#define ATOM_FDIM 133
#define BOND_FDIM 147
#define CATP 448
#define N_MOLS 2000

typedef __bf16 bf16x8 __attribute__((ext_vector_type(8)));
typedef float f32x4 __attribute__((ext_vector_type(4)));

__device__ __forceinline__ u16 f2bf(float f) {
    union { float f; u32 u; } x; x.f = f;
    u32 u = x.u;
    u32 r = u + 0x7fffu + ((u >> 16) & 1u);
    return (u16)(r >> 16);
}
__device__ __forceinline__ float bf2f(u16 h) {
    union { u32 u; float f; } x; x.u = ((u32)h) << 16;
    return x.f;
}

union U8 { uint4 v; u16 h[8]; };
union U4 { uint2 v; u16 h[4]; };

// ============ LDS-staged GEMM, 32 rows x 320 cols, LINEAR A only ============
// 256 threads = 4 waves (wave w = cols w*80). Stage A once (8 threads/row,
// all-linear loads), one barrier, then barrier-free k-loop: ds_read A +
// ring-of-3 global B prefetch + swapped-operand MFMA (lane holds 4 consecutive
// output cols). M must be a multiple of 32.
//  ASRC 0: linear bf16 rows, stride HP
//  ASRC 1: f32 rows (f_bonds, width 147), zero-pad
//  ASRC 3: cat [amsg row (304 cols, 300+ zero) | f32 f_atoms (133) | 0]
// EP 1: O1=bf16(acc)
// EP 2: O1=bf16(acc + inp_in)   (inp preloaded before k-loop)
// EP 3: O1=bf16(relu(acc + (col<Nout?bias:0)))
// EP 4: col<133 -> F1[row*133+col]=acc+bias[col]; 133<=col<147 ->
//       F2[row*16+col-133]=acc+bias2[col-133]
template<int ASRC, int EP, int KSTEPS>
__global__ __launch_bounds__(256, 4) void k_gemm_lds(
    const u16* __restrict__ srcA, const float* __restrict__ fsrc,
    const u16* __restrict__ Bt, int ldb, int Nout,
    const float* __restrict__ bias, const float* __restrict__ bias2,
    u16* __restrict__ O1, float* __restrict__ F1, float* __restrict__ F2,
    const u16* __restrict__ inp_in)
{
    constexpr int CHPR = KSTEPS * 4;
    constexpr int MASK = (CHPR % 8 == 0) ? 7 : 3;
    constexpr int CPT = (CHPR + 7) / 8;
    __shared__ __align__(16) u16 As[32 * CHPR * 8];

    const int tid = threadIdx.x;
    const int row0 = blockIdx.x * 32;

    // ---- stage A tile: 8 threads per row, linear loads ----
    {
        const int rr = tid >> 3;
        const int cc = tid & 7;
        const int row = row0 + rr;
        const u16* px = nullptr; const float* pf = nullptr;
        if constexpr (ASRC == 0) px = srcA + (size_t)row * HP;
        if constexpr (ASRC == 1) pf = fsrc + (size_t)row * BOND_FDIM;
        if constexpr (ASRC == 3) { px = srcA + (size_t)row * HP; pf = fsrc + (size_t)row * ATOM_FDIM; }
#pragma unroll
        for (int j = 0; j < CPT; j++) {
            const int c = cc + 8 * j;
            if (CPT * 8 != CHPR && c >= CHPR) continue;
            U8 u;
            if constexpr (ASRC == 0) {
                u.v = *(const uint4*)(px + c * 8);
            } else if constexpr (ASRC == 1) {
#pragma unroll
                for (int e = 0; e < 8; e++) {
                    int col = c * 8 + e;
                    u.h[e] = (col < BOND_FDIM) ? f2bf(pf[col]) : (u16)0;
                }
            } else {
                if (c < 38) {
                    u.v = *(const uint4*)(px + c * 8);
                } else {
#pragma unroll
                    for (int e = 0; e < 8; e++) {
                        int col = c * 8 + e - 304;
                        u.h[e] = (col >= 0 && col < ATOM_FDIM) ? f2bf(pf[col]) : (u16)0;
                    }
                }
            }
            *(uint4*)&As[(size_t)(rr * CHPR + (c ^ (rr & MASK))) * 8] = u.v;
        }
    }

    // ---- consumer setup ----
    const int lane = tid & 63;
    const int wv = tid >> 6;
    const int ncol0 = wv * 80;
    const int lrow = lane & 15;
    const int g = lane >> 4;
    const int lkb = g * 8;
    const int xr = lrow & MASK;

    const u16* pb[5];
#pragma unroll
    for (int n = 0; n < 5; n++)
        pb[n] = Bt + (size_t)(ncol0 + n * 16 + lrow) * ldb + lkb;

    // EP2: pre-issue epilogue inp loads (hidden under the k-loop)
    U4 ii[10];
    if constexpr (EP == 2) {
#pragma unroll
        for (int m = 0; m < 2; m++)
#pragma unroll
            for (int n = 0; n < 5; n++)
                ii[m * 5 + n].v = *(const uint2*)&inp_in[
                    (size_t)(row0 + m * 16 + lrow) * HP + ncol0 + n * 16 + g * 4];
    }

    __syncthreads();

    // ---- barrier-free MFMA loop, B 2-deep prefetch (ring of 3) ----
    f32x4 acc[2][5] = {};
    bf16x8 bb[3][5];
#pragma unroll
    for (int n = 0; n < 5; n++) bb[0][n] = *(const bf16x8*)(pb[n]);
    if constexpr (KSTEPS > 1) {
#pragma unroll
        for (int n = 0; n < 5; n++) bb[1][n] = *(const bf16x8*)(pb[n] + 32);
    }

#pragma unroll
    for (int ks = 0; ks < KSTEPS; ks++) {
        if (ks + 2 < KSTEPS) {
#pragma unroll
            for (int n = 0; n < 5; n++)
                bb[(ks + 2) % 3][n] = *(const bf16x8*)(pb[n] + (ks + 2) * 32);
        }
        const int sw = (ks * 4 + g) ^ xr;
        bf16x8 a0 = *(const bf16x8*)&As[(size_t)(lrow * CHPR + sw) * 8];
        bf16x8 a1 = *(const bf16x8*)&As[(size_t)((lrow + 16) * CHPR + sw) * 8];
#pragma unroll
        for (int n = 0; n < 5; n++) {
            acc[0][n] = __builtin_amdgcn_mfma_f32_16x16x32_bf16(bb[ks % 3][n], a0, acc[0][n], 0, 0, 0);
            acc[1][n] = __builtin_amdgcn_mfma_f32_16x16x32_bf16(bb[ks % 3][n], a1, acc[1][n], 0, 0, 0);
        }
    }

    // ---- epilogue ----
#pragma unroll
    for (int m = 0; m < 2; m++) {
        const int row = row0 + m * 16 + lrow;
#pragma unroll
        for (int n = 0; n < 5; n++) {
            const int colb = ncol0 + n * 16 + g * 4;
            if constexpr (EP == 4) {
                if (colb >= 148) continue;
#pragma unroll
                for (int q = 0; q < 4; q++) {
                    const int col = colb + q;
                    const float v = acc[m][n][q];
                    if (col < 133) F1[(size_t)row * 133 + col] = v + bias[col];
                    else if (col < 147) F2[(size_t)row * 16 + (col - 133)] = v + bias2[col - 133];
                }
            } else {
                U4 o;
                if constexpr (EP == 1) {
#pragma unroll
                    for (int q = 0; q < 4; q++) o.h[q] = f2bf(acc[m][n][q]);
                } else if constexpr (EP == 2) {
#pragma unroll
                    for (int q = 0; q < 4; q++) o.h[q] = f2bf(acc[m][n][q] + bf2f(ii[m * 5 + n].h[q]));
                } else {
#pragma unroll
                    for (int q = 0; q < 4; q++) {
                        float x = acc[m][n][q] + ((colb + q) < Nout ? bias[colb + q] : 0.f);
                        o.h[q] = f2bf(fmaxf(x, 0.f));
                    }
                }
                *(uint2*)&O1[(size_t)row * HP + colb] = o.v;
            }
        }
    }
}

// ---------------- weight pack: Bt[n][k] = W[k][n], bf16, zero-padded ----------------
__global__ void k_pack_wt(const float* __restrict__ W, u16* __restrict__ Bt,
                          int K, int N, int Kp, int Np)
{
    int idx = blockIdx.x * 256 + threadIdx.x;
    if (idx >= Np * Kp) return;
    int n = idx / Kp, k = idx - n * Kp;
    Bt[idx] = (n < N && k < K) ? f2bf(W[(size_t)k * N + n]) : (u16)0;
}

// W_o pack with the [amsg(300) | pad4 | f_atoms(133) | pad] column reorder
__global__ void k_pack_wo(const float* __restrict__ W, u16* __restrict__ Bt)
{
    int idx = blockIdx.x * 256 + threadIdx.x;
    if (idx >= 320 * CATP) return;
    int n = idx / CATP, k = idx - n * CATP;
    float v = 0.f;
    if (n < HIDDEN) {
        if (k < HIDDEN) v = W[(size_t)(ATOM_FDIM + k) * HIDDEN + n];
        else if (k >= 304 && k < 304 + ATOM_FDIM) v = W[(size_t)(k - 304) * HIDDEN + n];
    }
    Bt[idx] = f2bf(v);
}

// merged head pack: Bt_ne[n][k]: n<133 from W_node, 133<=n<147 from W_edge
__global__ void k_pack_wne(const float* __restrict__ Wn, const float* __restrict__ We,
                           u16* __restrict__ Bt)
{
    int idx = blockIdx.x * 256 + threadIdx.x;
    if (idx >= 320 * 320) return;
    int n = idx / 320, k = idx - n * 320;
    float v = 0.f;
    if (k < HIDDEN) {
        if (n < ATOM_FDIM) v = Wn[(size_t)k * ATOM_FDIM + n];
        else if (n < ATOM_FDIM + 14) v = We[(size_t)k * 14 + (n - ATOM_FDIM)];
    }
    Bt[idx] = f2bf(v);
}

// ---------------- a_msg[a] = sum_j relu(h[a2b[a][j]]) ----------------
__global__ __launch_bounds__(256) void k_aggregate(const u16* __restrict__ h,
    const int* __restrict__ a2b, u16* __restrict__ amsg)
{
    int idx = blockIdx.x * 256 + threadIdx.x;
    if (idx >= N_ATOMS * 40) return;
    int a = idx / 40, c = (idx - a * 40) * 8;
    float s[8] = {};
#pragma unroll
    for (int j = 0; j < 6; j++) {
        int b = a2b[a * 6 + j];
        U8 u; u.v = *(const uint4*)&h[(size_t)b * HP + c];
#pragma unroll
        for (int i = 0; i < 8; i++) s[i] += fmaxf(bf2f(u.h[i]), 0.f);
    }
    U8 o;
#pragma unroll
    for (int i = 0; i < 8; i++) o.h[i] = f2bf(s[i]);
    *(uint4*)&amsg[(size_t)a * HP + c] = o.v;
}

// -------- delta[b] = amsg[b2a[b]] - relu(h[b^1])   (streaming, gather here) --------
__global__ __launch_bounds__(256) void k_delta(const u16* __restrict__ amsg,
    const u16* __restrict__ h, const int* __restrict__ b2a, u16* __restrict__ dlt)
{
    int idx = blockIdx.x * 256 + threadIdx.x;
    if (idx >= N_BONDS * 40) return;
    int b = idx / 40, c = (idx - b * 40) * 8;
    int a = b2a[b];
    U8 x; x.v = *(const uint4*)&amsg[(size_t)a * HP + c];
    U8 y; y.v = *(const uint4*)&h[(size_t)(b ^ 1) * HP + c];
    U8 o;
#pragma unroll
    for (int i = 0; i < 8; i++)
        o.h[i] = f2bf(bf2f(x.h[i]) - fmaxf(bf2f(y.h[i]), 0.f));
    *(uint4*)&dlt[(size_t)b * HP + c] = o.v;
}

// -------- edge head finish: out[e] = 0.5*(E[b2a[2e]] + E[b2a[2e+1]]) --------
__global__ __launch_bounds__(256) void k_edge(const float* __restrict__ E,
    const int* __restrict__ b2a, float* __restrict__ out)
{
    int idx = blockIdx.x * 256 + threadIdx.x;
    if (idx >= N_EDGES * 7) return;
    int e = idx / 7, p = idx - e * 7;
    int a1 = b2a[2 * e], a2 = b2a[2 * e + 1];
    float2 x = *(const float2*)&E[(size_t)a1 * 16 + 2 * p];
    float2 y = *(const float2*)&E[(size_t)a2 * 16 + 2 * p];
    float2 o; o.x = 0.5f * (x.x + y.x); o.y = 0.5f * (x.y + y.y);
    *(float2*)&out[(size_t)e * 14 + 2 * p] = o;
}

// ---------------- per-molecule segment sum (graph_idx sorted) ----------------
__device__ __forceinline__ int lower_bound_i(const int* a, int n, int v) {
    int lo = 0, hi = n;
    while (lo < hi) { int mid = (lo + hi) >> 1; if (a[mid] < v) lo = mid + 1; else hi = mid; }
    return lo;
}
__global__ __launch_bounds__(320) void k_segsum(const u16* __restrict__ ah,
    const int* __restrict__ gidx, float* __restrict__ gemb)
{
    int g = blockIdx.x;
    int c = threadIdx.x;
    int s = lower_bound_i(gidx, N_ATOMS, g);
    int e = lower_bound_i(gidx, N_ATOMS, g + 1);
    float sum = 0.f;
    for (int a = s; a < e; a++) sum += bf2f(ah[(size_t)a * HP + c]);
    gemb[(size_t)g * HP + c] = sum;
}

// ---------------- graph head (fp32) ----------------
__global__ __launch_bounds__(320) void k_g1(const float* __restrict__ gemb,
    const float* __restrict__ W, const float* __restrict__ b, float* __restrict__ gh)
{
    int g = blockIdx.x, j = threadIdx.x;
    float acc = 0.f;
    if (j < HIDDEN) {
        acc = b[j];
        for (int k = 0; k < HIDDEN; k++)
            acc = fmaf(gemb[(size_t)g * HP + k], W[(size_t)k * HIDDEN + j], acc);
        acc = fmaxf(acc, 0.f);
    }
    gh[(size_t)g * HP + j] = (j < HIDDEN) ? acc : 0.f;
}
__global__ __launch_bounds__(64) void k_g2(const float* __restrict__ gh,
    const float* __restrict__ W, const float* __restrict__ b, float* __restrict__ out)
{
    int g = blockIdx.x, l = threadIdx.x;
    float acc = 0.f;
    for (int j = l; j < HIDDEN; j += 64) acc += gh[(size_t)g * HP + j] * W[j];
#pragma unroll
    for (int off = 32; off; off >>= 1) acc += __shfl_down(acc, off, 64);
    if (l == 0) out[g] = acc + b[0];
}

extern "C" void kernel_launch(void* const* d_in, const int* in_sizes, int n_in,
                              void* d_out, int out_size, void* d_ws, size_t ws_size,
                              hipStream_t stream)
{
    const float* f_atoms = (const float*)d_in[0];
    const float* f_bonds = (const float*)d_in[1];
    const int* a2b    = (const int*)d_in[2];
    const int* b2a    = (const int*)d_in[3];
    const int* gidx   = (const int*)d_in[5];
    const float* W_i    = (const float*)d_in[6];
    const float* W_h    = (const float*)d_in[7];
    const float* W_o    = (const float*)d_in[8];
    const float* b_o    = (const float*)d_in[9];
    const float* W_node = (const float*)d_in[10];
    const float* b_node = (const float*)d_in[11];
    const float* W_edge = (const float*)d_in[12];
    const float* b_edge = (const float*)d_in[13];
    const float* W_g1   = (const float*)d_in[14];
    const float* b_g1   = (const float*)d_in[15];
    const float* W_g2   = (const float*)d_in[16];
    const float* b_g2   = (const float*)d_in[17];

    char* ws = (char*)d_ws;
    u16* inp   = (u16*)(ws + 0);            // 128 MB (h1 pre-relu); later Ebuf
    u16* hA    = (u16*)(ws + 128000000);    // 128 MB: h2 -> h3
    u16* hB    = (u16*)(ws + 256000000);    // 128 MB: delta scratch -> ah
    u16* amsg  = (u16*)(ws + 384000000);    // 64 MB
    u16* wt_i  = (u16*)(ws + 448000000);    // 320x160
    u16* wt_h  = (u16*)(ws + 448200000);    // 320x320
    u16* wt_o  = (u16*)(ws + 448500000);    // 320x448
    u16* wt_ne = (u16*)(ws + 448800000);    // 320x320
    float* gemb = (float*)(ws + 449300000); // 2000x320 f32
    float* gh   = (float*)(ws + 452000000); // 2000x320 f32

    float* out_node  = (float*)d_out;
    float* out_edge  = out_node + (size_t)N_ATOMS * ATOM_FDIM;
    float* out_graph = out_node + 14700000;

    dim3 blk(256);

    // pack weights (bf16, transposed, zero-padded)
    k_pack_wt<<<(320 * 160 + 255) / 256, blk, 0, stream>>>(W_i, wt_i, BOND_FDIM, HIDDEN, 160, 320);
    k_pack_wt<<<(320 * 320 + 255) / 256, blk, 0, stream>>>(W_h, wt_h, HIDDEN, HIDDEN, 320, 320);
    k_pack_wo<<<(320 * CATP + 255) / 256, blk, 0, stream>>>(W_o, wt_o);
    k_pack_wne<<<(320 * 320 + 255) / 256, blk, 0, stream>>>(W_node, W_edge, wt_ne);

    const int gB32 = N_BONDS / 32;    // 6250
    const int gA32 = N_ATOMS / 32;    // 3125
    const int gAg = (N_ATOMS * 40 + 255) / 256;
    const int gDl = (N_BONDS * 40 + 255) / 256;

    // inp = f_bonds @ W_i  (f32 staged in-kernel; pre-relu stored)
    k_gemm_lds<1, 1, 5><<<gB32, blk, 0, stream>>>(
        nullptr, f_bonds, wt_i, 160, 0, nullptr, nullptr, inp, nullptr, nullptr, nullptr);

    // depth loop: h' = inp + delta @ W_h, delta built by streaming kernel
    // d=0: agg(inp)->amsg; delta(amsg,inp)->hB; gemm(hB)+inp -> hA
    // d=1: agg(hA)->amsg;  delta(amsg,hA)->hB;  gemm(hB)+inp -> hA (in place of dead h2)
    const u16* hcur = inp;
    for (int d = 0; d < 2; ++d) {
        k_aggregate<<<gAg, blk, 0, stream>>>(hcur, a2b, amsg);
        k_delta<<<gDl, blk, 0, stream>>>(amsg, hcur, b2a, hB);
        k_gemm_lds<0, 2, 10><<<gB32, blk, 0, stream>>>(
            hB, nullptr, wt_h, 320, 0, nullptr, nullptr, hA, nullptr, nullptr, inp);
        hcur = hA;
    }

    // final aggregate + fused-concat W_o -> atom_hiddens (relu'd, bf16) in hB
    k_aggregate<<<gAg, blk, 0, stream>>>(hcur, a2b, amsg);
    u16* ah = hB;   // delta scratch free
    k_gemm_lds<3, 3, 14><<<gA32, blk, 0, stream>>>(
        amsg, f_atoms, wt_o, CATP, HIDDEN, b_o, nullptr, ah, nullptr, nullptr, nullptr);

    // merged node+edge head: cols 0..132 -> node preds, 133..146 -> E buffer
    float* Ebuf = (float*)inp;   // inp dead after last gemm
    k_gemm_lds<0, 4, 10><<<gA32, blk, 0, stream>>>(
        ah, nullptr, wt_ne, 320, 0, b_node, b_edge, nullptr, out_node, Ebuf, nullptr);

    // edge head finish: average endpoint E rows
    k_edge<<<(N_EDGES * 7 + 255) / 256, blk, 0, stream>>>(Ebuf, b2a, out_edge);

    // graph head
    k_segsum<<<N_MOLS, 320, 0, stream>>>(ah, gidx, gemb);
    k_g1<<<N_MOLS, 320, 0, stream>>>(gemb, W_g1, b_g1, gh);
    k_g2<<<N_MOLS, 64, 0, stream>>>(gh, W_g2, b_g2, out_graph);
}

// Round 12
// 1155.970 us; speedup vs baseline: 1.0485x; 1.0485x over previous
//
#include <hip/hip_runtime.h>

typedef unsigned short u16;
typedef unsigned int u32;

#define N_ATOMS 100000
#define N_BONDS 200000
#define N_EDGES 100000
#define HIDDEN 300
#define HP 320
#define ATOM_FDIM 133
#define BOND_FDIM 147
#define CATP 448
#define N_MOLS 2000

typedef __bf16 bf16x8 __attribute__((ext_vector_type(8)));
typedef float f32x4 __attribute__((ext_vector_type(4)));

__device__ __forceinline__ u16 f2bf(float f) {
    union { float f; u32 u; } x; x.f = f;
    u32 u = x.u;
    u32 r = u + 0x7fffu + ((u >> 16) & 1u);
    return (u16)(r >> 16);
}
__device__ __forceinline__ float bf2f(u16 h) {
    union { u32 u; float f; } x; x.u = ((u32)h) << 16;
    return x.f;
}

union U8 { uint4 v; u16 h[8]; };
union U4 { uint2 v; u16 h[4]; };

// ============ R1-structure GEMM (proven 2.5 TB/s): 128 rows x 64 cols ============
// 256 threads = 4 waves (2x2). LDS-staged A+B per k-step (2 barriers/kstep),
// 1-deep linear prefetch, 40-elem padded LDS rows (2-way conflicts = free).
// Work order: N-block fastest within linear wg; bijective XCD swizzle (m204)
// so the NB blocks sharing one A-panel land on the same XCD's L2.
// Swapped-operand MFMA: lane holds 4 CONSECUTIVE output cols -> uint2 stores.
//  ASRC 0: linear bf16 rows, stride HP
//  ASRC 1: f32 rows (f_bonds, width 147), zero-pad to K
//  ASRC 3: cat [amsg row (304 cols, 300+ zero) | f32 f_atoms (133) | 0 pad]
// EP 1: O1=bf16(acc)
// EP 2: O1=bf16(acc + inp_in)          (uint2 read in epilogue)
// EP 3: O1=bf16(relu(acc + (col<Nout?bias:0)))
// EP 4: col<133 -> F1[row*133+col]=acc+bias[col] (f32 node preds)
//       133<=col<147 -> F2[row*16+col-133]=acc+bias2[col-133] (E buffer)
template<int ASRC, int EP, int KSTEPS, int NB>
__global__ __launch_bounds__(256) void k_gemmR(
    const u16* __restrict__ srcA, const float* __restrict__ fsrc,
    int M, const u16* __restrict__ Bt, int ldb, int Nout,
    const float* __restrict__ bias, const float* __restrict__ bias2,
    u16* __restrict__ O1, float* __restrict__ F1, float* __restrict__ F2,
    const u16* __restrict__ inp_in, int nwg)
{
    __shared__ __align__(16) u16 As[128 * 40];
    __shared__ __align__(16) u16 Bs[64 * 40];

    // bijective XCD-chunk swizzle: bid%8 = XCD -> contiguous work chunk
    const int bid = blockIdx.x;
    const int q = nwg >> 3, r = nwg & 7;
    const int xcd = bid & 7, sidx = bid >> 3;
    const int wg = (xcd < r ? xcd * (q + 1) : r * (q + 1) + (xcd - r) * q) + sidx;

    const int n0 = (wg % NB) * 64;
    const int row0 = (wg / NB) * 128;

    const int tid = threadIdx.x;
    const int lane = tid & 63;
    const int w = tid >> 6, wr = w >> 1, wc = w & 1;
    const int lrow = lane & 15;
    const int g = lane >> 4;
    const int lkb = g * 8;

    // staging map: A = 128 rows x 4 kgroups (2 chunks/thread), B = 64 x 4
    const int rA0 = tid >> 2, kg = tid & 3, kofs = kg * 8;
    const int rA1 = rA0 + 64;
    int r0 = row0 + rA0; if (r0 >= M) r0 = M - 1;
    int r1 = row0 + rA1; if (r1 >= M) r1 = M - 1;

    auto loadA = [&](int rr, int k0) -> uint4 {
        U8 u;
        if constexpr (ASRC == 0) {
            u.v = *(const uint4*)(srcA + (size_t)rr * HP + k0 + kofs);
        } else if constexpr (ASRC == 1) {
            size_t fb = (size_t)rr * BOND_FDIM;
#pragma unroll
            for (int e = 0; e < 8; e++) {
                int col = k0 + kofs + e;
                u.h[e] = (col < BOND_FDIM) ? f2bf(fsrc[fb + col]) : (u16)0;
            }
        } else {
            int col0 = k0 + kofs;
            if (col0 < 304) {
                u.v = *(const uint4*)(srcA + (size_t)rr * HP + col0);
            } else {
                size_t fb = (size_t)rr * ATOM_FDIM;
#pragma unroll
                for (int e = 0; e < 8; e++) {
                    int col = col0 + e - 304;
                    u.h[e] = (col < ATOM_FDIM) ? f2bf(fsrc[fb + col]) : (u16)0;
                }
            }
        }
        return u.v;
    };

    const u16* pb = Bt + (size_t)(n0 + rA0) * ldb + kofs;

    uint4 va0 = loadA(r0, 0);
    uint4 va1 = loadA(r1, 0);
    uint4 vb  = *(const uint4*)pb;

    f32x4 acc[4][2] = {};

    constexpr int K = KSTEPS * 32;
    for (int k0 = 0; k0 < K; k0 += 32) {
        *(uint4*)&As[rA0 * 40 + kofs] = va0;
        *(uint4*)&As[rA1 * 40 + kofs] = va1;
        *(uint4*)&Bs[rA0 * 40 + kofs] = vb;
        __syncthreads();
        if (k0 + 32 < K) {
            va0 = loadA(r0, k0 + 32);
            va1 = loadA(r1, k0 + 32);
            vb  = *(const uint4*)(pb + k0 + 32);
        }
        bf16x8 af[4], bfr[2];
#pragma unroll
        for (int m = 0; m < 4; m++)
            af[m] = *(const bf16x8*)&As[(wr * 64 + m * 16 + lrow) * 40 + lkb];
#pragma unroll
        for (int n = 0; n < 2; n++)
            bfr[n] = *(const bf16x8*)&Bs[(wc * 32 + n * 16 + lrow) * 40 + lkb];
#pragma unroll
        for (int m = 0; m < 4; m++)
#pragma unroll
            for (int n = 0; n < 2; n++)
                acc[m][n] = __builtin_amdgcn_mfma_f32_16x16x32_bf16(bfr[n], af[m], acc[m][n], 0, 0, 0);
        __syncthreads();
    }

    // epilogue: row = row0+wr*64+m*16+lrow ; cols = n0+wc*32+n*16+g*4+q
#pragma unroll
    for (int m = 0; m < 4; m++) {
        const int row = row0 + wr * 64 + m * 16 + lrow;
        if (row >= M) continue;
#pragma unroll
        for (int n = 0; n < 2; n++) {
            const int colb = n0 + wc * 32 + n * 16 + g * 4;
            if constexpr (EP == 4) {
                if (colb >= 148) continue;
#pragma unroll
                for (int qq = 0; qq < 4; qq++) {
                    const int col = colb + qq;
                    const float v = acc[m][n][qq];
                    if (col < 133) F1[(size_t)row * 133 + col] = v + bias[col];
                    else if (col < 147) F2[(size_t)row * 16 + (col - 133)] = v + bias2[col - 133];
                }
            } else {
                U4 o;
                if constexpr (EP == 1) {
#pragma unroll
                    for (int qq = 0; qq < 4; qq++) o.h[qq] = f2bf(acc[m][n][qq]);
                } else if constexpr (EP == 2) {
                    U4 ii; ii.v = *(const uint2*)&inp_in[(size_t)row * HP + colb];
#pragma unroll
                    for (int qq = 0; qq < 4; qq++) o.h[qq] = f2bf(acc[m][n][qq] + bf2f(ii.h[qq]));
                } else {
#pragma unroll
                    for (int qq = 0; qq < 4; qq++) {
                        float x = acc[m][n][qq] + ((colb + qq) < Nout ? bias[colb + qq] : 0.f);
                        o.h[qq] = f2bf(fmaxf(x, 0.f));
                    }
                }
                *(uint2*)&O1[(size_t)row * HP + colb] = o.v;
            }
        }
    }
}

// ---------------- weight pack: Bt[n][k] = W[k][n], bf16, zero-padded ----------------
__global__ void k_pack_wt(const float* __restrict__ W, u16* __restrict__ Bt,
                          int K, int N, int Kp, int Np)
{
    int idx = blockIdx.x * 256 + threadIdx.x;
    if (idx >= Np * Kp) return;
    int n = idx / Kp, k = idx - n * Kp;
    Bt[idx] = (n < N && k < K) ? f2bf(W[(size_t)k * N + n]) : (u16)0;
}

// W_o pack with the [amsg(300) | pad4 | f_atoms(133) | pad] column reorder
__global__ void k_pack_wo(const float* __restrict__ W, u16* __restrict__ Bt)
{
    int idx = blockIdx.x * 256 + threadIdx.x;
    if (idx >= 320 * CATP) return;
    int n = idx / CATP, k = idx - n * CATP;
    float v = 0.f;
    if (n < HIDDEN) {
        if (k < HIDDEN) v = W[(size_t)(ATOM_FDIM + k) * HIDDEN + n];
        else if (k >= 304 && k < 304 + ATOM_FDIM) v = W[(size_t)(k - 304) * HIDDEN + n];
    }
    Bt[idx] = f2bf(v);
}

// merged head pack: Bt_ne[n][k]: n<133 from W_node, 133<=n<147 from W_edge
__global__ void k_pack_wne(const float* __restrict__ Wn, const float* __restrict__ We,
                           u16* __restrict__ Bt)
{
    int idx = blockIdx.x * 256 + threadIdx.x;
    if (idx >= 320 * 320) return;
    int n = idx / 320, k = idx - n * 320;
    float v = 0.f;
    if (k < HIDDEN) {
        if (n < ATOM_FDIM) v = Wn[(size_t)k * ATOM_FDIM + n];
        else if (n < ATOM_FDIM + 14) v = We[(size_t)k * 14 + (n - ATOM_FDIM)];
    }
    Bt[idx] = f2bf(v);
}

// ---------------- a_msg[a] = sum_j relu(h[a2b[a][j]]) ----------------
__global__ __launch_bounds__(256) void k_aggregate(const u16* __restrict__ h,
    const int* __restrict__ a2b, u16* __restrict__ amsg)
{
    int idx = blockIdx.x * 256 + threadIdx.x;
    if (idx >= N_ATOMS * 40) return;
    int a = idx / 40, c = (idx - a * 40) * 8;
    float s[8] = {};
#pragma unroll
    for (int j = 0; j < 6; j++) {
        int b = a2b[a * 6 + j];
        U8 u; u.v = *(const uint4*)&h[(size_t)b * HP + c];
#pragma unroll
        for (int i = 0; i < 8; i++) s[i] += fmaxf(bf2f(u.h[i]), 0.f);
    }
    U8 o;
#pragma unroll
    for (int i = 0; i < 8; i++) o.h[i] = f2bf(s[i]);
    *(uint4*)&amsg[(size_t)a * HP + c] = o.v;
}

// -------- delta[b] = amsg[b2a[b]] - relu(h[b^1])   (streaming, gathers here) --------
__global__ __launch_bounds__(256) void k_delta(const u16* __restrict__ amsg,
    const u16* __restrict__ h, const int* __restrict__ b2a, u16* __restrict__ dlt)
{
    int idx = blockIdx.x * 256 + threadIdx.x;
    if (idx >= N_BONDS * 40) return;
    int b = idx / 40, c = (idx - b * 40) * 8;
    int a = b2a[b];
    U8 x; x.v = *(const uint4*)&amsg[(size_t)a * HP + c];
    U8 y; y.v = *(const uint4*)&h[(size_t)(b ^ 1) * HP + c];
    U8 o;
#pragma unroll
    for (int i = 0; i < 8; i++)
        o.h[i] = f2bf(bf2f(x.h[i]) - fmaxf(bf2f(y.h[i]), 0.f));
    *(uint4*)&dlt[(size_t)b * HP + c] = o.v;
}

// -------- edge head finish: out[e] = 0.5*(E[b2a[2e]] + E[b2a[2e+1]]) --------
__global__ __launch_bounds__(256) void k_edge(const float* __restrict__ E,
    const int* __restrict__ b2a, float* __restrict__ out)
{
    int idx = blockIdx.x * 256 + threadIdx.x;
    if (idx >= N_EDGES * 7) return;
    int e = idx / 7, p = idx - e * 7;
    int a1 = b2a[2 * e], a2 = b2a[2 * e + 1];
    float2 x = *(const float2*)&E[(size_t)a1 * 16 + 2 * p];
    float2 y = *(const float2*)&E[(size_t)a2 * 16 + 2 * p];
    float2 o; o.x = 0.5f * (x.x + y.x); o.y = 0.5f * (x.y + y.y);
    *(float2*)&out[(size_t)e * 14 + 2 * p] = o;
}

// ---------------- per-molecule segment sum (graph_idx sorted) ----------------
__device__ __forceinline__ int lower_bound_i(const int* a, int n, int v) {
    int lo = 0, hi = n;
    while (lo < hi) { int mid = (lo + hi) >> 1; if (a[mid] < v) lo = mid + 1; else hi = mid; }
    return lo;
}
__global__ __launch_bounds__(320) void k_segsum(const u16* __restrict__ ah,
    const int* __restrict__ gidx, float* __restrict__ gemb)
{
    int g = blockIdx.x;
    int c = threadIdx.x;
    int s = lower_bound_i(gidx, N_ATOMS, g);
    int e = lower_bound_i(gidx, N_ATOMS, g + 1);
    float sum = 0.f;
    for (int a = s; a < e; a++) sum += bf2f(ah[(size_t)a * HP + c]);
    gemb[(size_t)g * HP + c] = sum;
}

// ---------------- graph head (fp32) ----------------
__global__ __launch_bounds__(320) void k_g1(const float* __restrict__ gemb,
    const float* __restrict__ W, const float* __restrict__ b, float* __restrict__ gh)
{
    int g = blockIdx.x, j = threadIdx.x;
    float acc = 0.f;
    if (j < HIDDEN) {
        acc = b[j];
        for (int k = 0; k < HIDDEN; k++)
            acc = fmaf(gemb[(size_t)g * HP + k], W[(size_t)k * HIDDEN + j], acc);
        acc = fmaxf(acc, 0.f);
    }
    gh[(size_t)g * HP + j] = (j < HIDDEN) ? acc : 0.f;
}
__global__ __launch_bounds__(64) void k_g2(const float* __restrict__ gh,
    const float* __restrict__ W, const float* __restrict__ b, float* __restrict__ out)
{
    int g = blockIdx.x, l = threadIdx.x;
    float acc = 0.f;
    for (int j = l; j < HIDDEN; j += 64) acc += gh[(size_t)g * HP + j] * W[j];
#pragma unroll
    for (int off = 32; off; off >>= 1) acc += __shfl_down(acc, off, 64);
    if (l == 0) out[g] = acc + b[0];
}

extern "C" void kernel_launch(void* const* d_in, const int* in_sizes, int n_in,
                              void* d_out, int out_size, void* d_ws, size_t ws_size,
                              hipStream_t stream)
{
    const float* f_atoms = (const float*)d_in[0];
    const float* f_bonds = (const float*)d_in[1];
    const int* a2b    = (const int*)d_in[2];
    const int* b2a    = (const int*)d_in[3];
    const int* gidx   = (const int*)d_in[5];
    const float* W_i    = (const float*)d_in[6];
    const float* W_h    = (const float*)d_in[7];
    const float* W_o    = (const float*)d_in[8];
    const float* b_o    = (const float*)d_in[9];
    const float* W_node = (const float*)d_in[10];
    const float* b_node = (const float*)d_in[11];
    const float* W_edge = (const float*)d_in[12];
    const float* b_edge = (const float*)d_in[13];
    const float* W_g1   = (const float*)d_in[14];
    const float* b_g1   = (const float*)d_in[15];
    const float* W_g2   = (const float*)d_in[16];
    const float* b_g2   = (const float*)d_in[17];

    char* ws = (char*)d_ws;
    u16* inp   = (u16*)(ws + 0);            // 128 MB (h1 pre-relu); later Ebuf
    u16* hA    = (u16*)(ws + 128000000);    // 128 MB: h2 -> h3
    u16* hB    = (u16*)(ws + 256000000);    // 128 MB: delta scratch -> ah
    u16* amsg  = (u16*)(ws + 384000000);    // 64 MB
    u16* wt_i  = (u16*)(ws + 448000000);    // 320x160
    u16* wt_h  = (u16*)(ws + 448200000);    // 320x320
    u16* wt_o  = (u16*)(ws + 448500000);    // 320x448
    u16* wt_ne = (u16*)(ws + 448800000);    // 320x320
    float* gemb = (float*)(ws + 449300000); // 2000x320 f32
    float* gh   = (float*)(ws + 452000000); // 2000x320 f32

    float* out_node  = (float*)d_out;
    float* out_edge  = out_node + (size_t)N_ATOMS * ATOM_FDIM;
    float* out_graph = out_node + 14700000;

    dim3 blk(256);

    // pack weights (bf16, transposed, zero-padded)
    k_pack_wt<<<(320 * 160 + 255) / 256, blk, 0, stream>>>(W_i, wt_i, BOND_FDIM, HIDDEN, 160, 320);
    k_pack_wt<<<(320 * 320 + 255) / 256, blk, 0, stream>>>(W_h, wt_h, HIDDEN, HIDDEN, 320, 320);
    k_pack_wo<<<(320 * CATP + 255) / 256, blk, 0, stream>>>(W_o, wt_o);
    k_pack_wne<<<(320 * 320 + 255) / 256, blk, 0, stream>>>(W_node, W_edge, wt_ne);

    const int mbB = (N_BONDS + 127) / 128;  // 1563
    const int mbA = (N_ATOMS + 127) / 128;  // 782
    const int gAg = (N_ATOMS * 40 + 255) / 256;
    const int gDl = (N_BONDS * 40 + 255) / 256;

    const int nwgI = 5 * mbB;   // W_i / W_h grids
    const int nwgO = 5 * mbA;   // W_o
    const int nwgH = 3 * mbA;   // merged head

    // inp = f_bonds @ W_i  (f32 staged in-kernel; pre-relu stored)
    k_gemmR<1, 1, 5, 5><<<nwgI, blk, 0, stream>>>(
        nullptr, f_bonds, N_BONDS, wt_i, 160, 0, nullptr, nullptr,
        inp, nullptr, nullptr, nullptr, nwgI);

    // depth loop: h' = inp + delta @ W_h; delta built by streaming kernel
    const u16* hcur = inp;
    for (int d = 0; d < 2; ++d) {
        k_aggregate<<<gAg, blk, 0, stream>>>(hcur, a2b, amsg);
        k_delta<<<gDl, blk, 0, stream>>>(amsg, hcur, b2a, hB);
        k_gemmR<0, 2, 10, 5><<<nwgI, blk, 0, stream>>>(
            hB, nullptr, N_BONDS, wt_h, 320, 0, nullptr, nullptr,
            hA, nullptr, nullptr, inp, nwgI);
        hcur = hA;
    }

    // final aggregate + fused-concat W_o -> atom_hiddens (relu'd, bf16) in hB
    k_aggregate<<<gAg, blk, 0, stream>>>(hcur, a2b, amsg);
    u16* ah = hB;   // delta scratch free
    k_gemmR<3, 3, 14, 5><<<nwgO, blk, 0, stream>>>(
        amsg, f_atoms, N_ATOMS, wt_o, CATP, HIDDEN, b_o, nullptr,
        ah, nullptr, nullptr, nullptr, nwgO);

    // merged node+edge head: cols 0..132 -> node preds, 133..146 -> E buffer
    float* Ebuf = (float*)inp;   // inp dead after last W_h gemm
    k_gemmR<0, 4, 10, 3><<<nwgH, blk, 0, stream>>>(
        ah, nullptr, N_ATOMS, wt_ne, 320, 0, b_node, b_edge,
        nullptr, out_node, Ebuf, nullptr, nwgH);

    // edge head finish: average endpoint E rows
    k_edge<<<(N_EDGES * 7 + 255) / 256, blk, 0, stream>>>(Ebuf, b2a, out_edge);

    // graph head
    k_segsum<<<N_MOLS, 320, 0, stream>>>(ah, gidx, gemb);
    k_g1<<<N_MOLS, 320, 0, stream>>>(gemb, W_g1, b_g1, gh);
    k_g2<<<N_MOLS, 64, 0, stream>>>(gh, W_g2, b_g2, out_graph);
}

// Round 13
// 1143.054 us; speedup vs baseline: 1.0604x; 1.0113x over previous
//
#include <hip/hip_runtime.h>

typedef unsigned short u16;
typedef unsigned int u32;

#define N_ATOMS 100000
#define N_BONDS 200000
#define N_EDGES 100000
#define HIDDEN 300
#define HP 320
#define ATOM_FDIM 133
#define BOND_FDIM 147
#define CATP 448
#define N_MOLS 2000

typedef __bf16 bf16x8 __attribute__((ext_vector_type(8)));
typedef float f32x4 __attribute__((ext_vector_type(4)));

__device__ __forceinline__ u16 f2bf(float f) {
    union { float f; u32 u; } x; x.f = f;
    u32 u = x.u;
    u32 r = u + 0x7fffu + ((u >> 16) & 1u);
    return (u16)(r >> 16);
}
__device__ __forceinline__ float bf2f(u16 h) {
    union { u32 u; float f; } x; x.u = ((u32)h) << 16;
    return x.f;
}

union U8 { uint4 v; u16 h[8]; };
union U4 { uint2 v; u16 h[4]; };

// ============ R1-structure GEMM (proven 2.5 TB/s): 128 rows x 64 cols ============
// 256 threads = 4 waves (2x2). LDS-staged A+B per k-step (2 barriers/kstep),
// 1-deep linear prefetch, 40-elem padded LDS rows (2-way conflicts = free).
// N-block fastest work order + bijective XCD swizzle (m204) for A-panel L2 reuse.
// Swapped-operand MFMA: lane holds 4 CONSECUTIVE output cols -> uint2 stores.
//  ASRC 0: linear bf16 rows, stride HP
//  ASRC 1: f32 rows (f_bonds, width 147), zero-pad to K
//  ASRC 3: cat [amsg row (304 cols, 300+ zero) | f32 f_atoms (133) | 0 pad]
// EP 1: O1=bf16(acc)
// EP 2: O1=bf16(acc + inp_in)          (uint2 read in epilogue)
// EP 3: O1=bf16(relu(acc + (col<Nout?bias:0)))
// EP 4: merged head, LDS-bounce coalesced f32 epilogue:
//       col<133 -> F1[row*133+col]=acc+bias[col]; 133<=col<147 ->
//       F2[row*16+col-133]=acc+bias2[col-133]
template<int ASRC, int EP, int KSTEPS, int NB>
__global__ __launch_bounds__(256) void k_gemmR(
    const u16* __restrict__ srcA, const float* __restrict__ fsrc,
    int M, const u16* __restrict__ Bt, int ldb, int Nout,
    const float* __restrict__ bias, const float* __restrict__ bias2,
    u16* __restrict__ O1, float* __restrict__ F1, float* __restrict__ F2,
    const u16* __restrict__ inp_in, int nwg)
{
    __shared__ __align__(16) u16 As[128 * 40];
    __shared__ __align__(16) u16 Bs[64 * 40];

    // bijective XCD-chunk swizzle: bid%8 = XCD -> contiguous work chunk
    const int bid = blockIdx.x;
    const int q = nwg >> 3, r = nwg & 7;
    const int xcd = bid & 7, sidx = bid >> 3;
    const int wg = (xcd < r ? xcd * (q + 1) : r * (q + 1) + (xcd - r) * q) + sidx;

    const int n0 = (wg % NB) * 64;
    const int row0 = (wg / NB) * 128;

    const int tid = threadIdx.x;
    const int lane = tid & 63;
    const int w = tid >> 6, wr = w >> 1, wc = w & 1;
    const int lrow = lane & 15;
    const int g = lane >> 4;
    const int lkb = g * 8;

    // staging map: A = 128 rows x 4 kgroups (2 chunks/thread), B = 64 x 4
    const int rA0 = tid >> 2, kg = tid & 3, kofs = kg * 8;
    const int rA1 = rA0 + 64;
    int r0 = row0 + rA0; if (r0 >= M) r0 = M - 1;
    int r1 = row0 + rA1; if (r1 >= M) r1 = M - 1;

    auto loadA = [&](int rr, int k0) -> uint4 {
        U8 u;
        if constexpr (ASRC == 0) {
            u.v = *(const uint4*)(srcA + (size_t)rr * HP + k0 + kofs);
        } else if constexpr (ASRC == 1) {
            size_t fb = (size_t)rr * BOND_FDIM;
#pragma unroll
            for (int e = 0; e < 8; e++) {
                int col = k0 + kofs + e;
                u.h[e] = (col < BOND_FDIM) ? f2bf(fsrc[fb + col]) : (u16)0;
            }
        } else {
            int col0 = k0 + kofs;
            if (col0 < 304) {
                u.v = *(const uint4*)(srcA + (size_t)rr * HP + col0);
            } else {
                size_t fb = (size_t)rr * ATOM_FDIM;
#pragma unroll
                for (int e = 0; e < 8; e++) {
                    int col = col0 + e - 304;
                    u.h[e] = (col < ATOM_FDIM) ? f2bf(fsrc[fb + col]) : (u16)0;
                }
            }
        }
        return u.v;
    };

    const u16* pb = Bt + (size_t)(n0 + rA0) * ldb + kofs;

    uint4 va0 = loadA(r0, 0);
    uint4 va1 = loadA(r1, 0);
    uint4 vb  = *(const uint4*)pb;

    f32x4 acc[4][2] = {};

    constexpr int K = KSTEPS * 32;
    for (int k0 = 0; k0 < K; k0 += 32) {
        *(uint4*)&As[rA0 * 40 + kofs] = va0;
        *(uint4*)&As[rA1 * 40 + kofs] = va1;
        *(uint4*)&Bs[rA0 * 40 + kofs] = vb;
        __syncthreads();
        if (k0 + 32 < K) {
            va0 = loadA(r0, k0 + 32);
            va1 = loadA(r1, k0 + 32);
            vb  = *(const uint4*)(pb + k0 + 32);
        }
        bf16x8 af[4], bfr[2];
#pragma unroll
        for (int m = 0; m < 4; m++)
            af[m] = *(const bf16x8*)&As[(wr * 64 + m * 16 + lrow) * 40 + lkb];
#pragma unroll
        for (int n = 0; n < 2; n++)
            bfr[n] = *(const bf16x8*)&Bs[(wc * 32 + n * 16 + lrow) * 40 + lkb];
#pragma unroll
        for (int m = 0; m < 4; m++)
#pragma unroll
            for (int n = 0; n < 2; n++)
                acc[m][n] = __builtin_amdgcn_mfma_f32_16x16x32_bf16(bfr[n], af[m], acc[m][n], 0, 0, 0);
        __syncthreads();
    }

    if constexpr (EP == 4) {
        // ---- LDS-bounce coalesced epilogue: 32x64 f32 slice per m ----
        // stride 68 (mult of 4 for f32x4 alignment; %32==4 -> bank spread)
        float* LDSf = (float*)As;   // 32*68*4 = 8704 B <= sizeof(As)
#pragma unroll
        for (int m = 0; m < 4; m++) {
            __syncthreads();
#pragma unroll
            for (int n = 0; n < 2; n++)
                *(f32x4*)&LDSf[(size_t)(wr * 16 + lrow) * 68 + wc * 32 + n * 16 + g * 4] = acc[m][n];
            __syncthreads();
#pragma unroll
            for (int i = 0; i < 8; i++) {
                const int rl = w + i * 4;                       // 0..31
                const int grow = row0 + ((rl & 16) ? 64 : 0) + m * 16 + (rl & 15);
                const float v = LDSf[(size_t)rl * 68 + lane];
                const int col = n0 + lane;                      // lane = column -> coalesced
                if (grow < M) {
                    if (col < 133) F1[(size_t)grow * 133 + col] = v + bias[col];
                    else if (col < 147) F2[(size_t)grow * 16 + (col - 133)] = v + bias2[col - 133];
                }
            }
        }
    } else {
        // epilogue: row = row0+wr*64+m*16+lrow ; cols = n0+wc*32+n*16+g*4+q
#pragma unroll
        for (int m = 0; m < 4; m++) {
            const int row = row0 + wr * 64 + m * 16 + lrow;
            if (row >= M) continue;
#pragma unroll
            for (int n = 0; n < 2; n++) {
                const int colb = n0 + wc * 32 + n * 16 + g * 4;
                U4 o;
                if constexpr (EP == 1) {
#pragma unroll
                    for (int qq = 0; qq < 4; qq++) o.h[qq] = f2bf(acc[m][n][qq]);
                } else if constexpr (EP == 2) {
                    U4 ii; ii.v = *(const uint2*)&inp_in[(size_t)row * HP + colb];
#pragma unroll
                    for (int qq = 0; qq < 4; qq++) o.h[qq] = f2bf(acc[m][n][qq] + bf2f(ii.h[qq]));
                } else {
#pragma unroll
                    for (int qq = 0; qq < 4; qq++) {
                        float x = acc[m][n][qq] + ((colb + qq) < Nout ? bias[colb + qq] : 0.f);
                        o.h[qq] = f2bf(fmaxf(x, 0.f));
                    }
                }
                *(uint2*)&O1[(size_t)row * HP + colb] = o.v;
            }
        }
    }
}

// ---------------- weight pack: Bt[n][k] = W[k][n], bf16, zero-padded ----------------
__global__ void k_pack_wt(const float* __restrict__ W, u16* __restrict__ Bt,
                          int K, int N, int Kp, int Np)
{
    int idx = blockIdx.x * 256 + threadIdx.x;
    if (idx >= Np * Kp) return;
    int n = idx / Kp, k = idx - n * Kp;
    Bt[idx] = (n < N && k < K) ? f2bf(W[(size_t)k * N + n]) : (u16)0;
}

// W_o pack with the [amsg(300) | pad4 | f_atoms(133) | pad] column reorder
__global__ void k_pack_wo(const float* __restrict__ W, u16* __restrict__ Bt)
{
    int idx = blockIdx.x * 256 + threadIdx.x;
    if (idx >= 320 * CATP) return;
    int n = idx / CATP, k = idx - n * CATP;
    float v = 0.f;
    if (n < HIDDEN) {
        if (k < HIDDEN) v = W[(size_t)(ATOM_FDIM + k) * HIDDEN + n];
        else if (k >= 304 && k < 304 + ATOM_FDIM) v = W[(size_t)(k - 304) * HIDDEN + n];
    }
    Bt[idx] = f2bf(v);
}

// merged head pack: Bt_ne[n][k]: n<133 from W_node, 133<=n<147 from W_edge
__global__ void k_pack_wne(const float* __restrict__ Wn, const float* __restrict__ We,
                           u16* __restrict__ Bt)
{
    int idx = blockIdx.x * 256 + threadIdx.x;
    if (idx >= 320 * 320) return;
    int n = idx / 320, k = idx - n * 320;
    float v = 0.f;
    if (k < HIDDEN) {
        if (n < ATOM_FDIM) v = Wn[(size_t)k * ATOM_FDIM + n];
        else if (n < ATOM_FDIM + 14) v = We[(size_t)k * 14 + (n - ATOM_FDIM)];
    }
    Bt[idx] = f2bf(v);
}

// ---------------- a_msg[a] = sum_j relu(h[a2b[a][j]]) ----------------
__global__ __launch_bounds__(256) void k_aggregate(const u16* __restrict__ h,
    const int* __restrict__ a2b, u16* __restrict__ amsg)
{
    int idx = blockIdx.x * 256 + threadIdx.x;
    if (idx >= N_ATOMS * 40) return;
    int a = idx / 40, c = (idx - a * 40) * 8;
    float s[8] = {};
#pragma unroll
    for (int j = 0; j < 6; j++) {
        int b = a2b[a * 6 + j];
        U8 u; u.v = *(const uint4*)&h[(size_t)b * HP + c];
#pragma unroll
        for (int i = 0; i < 8; i++) s[i] += fmaxf(bf2f(u.h[i]), 0.f);
    }
    U8 o;
#pragma unroll
    for (int i = 0; i < 8; i++) o.h[i] = f2bf(s[i]);
    *(uint4*)&amsg[(size_t)a * HP + c] = o.v;
}

// -------- delta[b] = amsg[b2a[b]] - relu(h[b^1])   (streaming, gathers here) --------
__global__ __launch_bounds__(256) void k_delta(const u16* __restrict__ amsg,
    const u16* __restrict__ h, const int* __restrict__ b2a, u16* __restrict__ dlt)
{
    int idx = blockIdx.x * 256 + threadIdx.x;
    if (idx >= N_BONDS * 40) return;
    int b = idx / 40, c = (idx - b * 40) * 8;
    int a = b2a[b];
    U8 x; x.v = *(const uint4*)&amsg[(size_t)a * HP + c];
    U8 y; y.v = *(const uint4*)&h[(size_t)(b ^ 1) * HP + c];
    U8 o;
#pragma unroll
    for (int i = 0; i < 8; i++)
        o.h[i] = f2bf(bf2f(x.h[i]) - fmaxf(bf2f(y.h[i]), 0.f));
    *(uint4*)&dlt[(size_t)b * HP + c] = o.v;
}

// -------- edge head finish: out[e] = 0.5*(E[b2a[2e]] + E[b2a[2e+1]]) --------
__global__ __launch_bounds__(256) void k_edge(const float* __restrict__ E,
    const int* __restrict__ b2a, float* __restrict__ out)
{
    int idx = blockIdx.x * 256 + threadIdx.x;
    if (idx >= N_EDGES * 7) return;
    int e = idx / 7, p = idx - e * 7;
    int a1 = b2a[2 * e], a2 = b2a[2 * e + 1];
    float2 x = *(const float2*)&E[(size_t)a1 * 16 + 2 * p];
    float2 y = *(const float2*)&E[(size_t)a2 * 16 + 2 * p];
    float2 o; o.x = 0.5f * (x.x + y.x); o.y = 0.5f * (x.y + y.y);
    *(float2*)&out[(size_t)e * 14 + 2 * p] = o;
}

// ---------------- per-molecule segment sum (graph_idx sorted) ----------------
__device__ __forceinline__ int lower_bound_i(const int* a, int n, int v) {
    int lo = 0, hi = n;
    while (lo < hi) { int mid = (lo + hi) >> 1; if (a[mid] < v) lo = mid + 1; else hi = mid; }
    return lo;
}
__global__ __launch_bounds__(320) void k_segsum(const u16* __restrict__ ah,
    const int* __restrict__ gidx, float* __restrict__ gemb)
{
    int g = blockIdx.x;
    int c = threadIdx.x;
    int s = lower_bound_i(gidx, N_ATOMS, g);
    int e = lower_bound_i(gidx, N_ATOMS, g + 1);
    float sum = 0.f;
    for (int a = s; a < e; a++) sum += bf2f(ah[(size_t)a * HP + c]);
    gemb[(size_t)g * HP + c] = sum;
}

// ---------------- graph head (fp32) ----------------
__global__ __launch_bounds__(320) void k_g1(const float* __restrict__ gemb,
    const float* __restrict__ W, const float* __restrict__ b, float* __restrict__ gh)
{
    int g = blockIdx.x, j = threadIdx.x;
    float acc = 0.f;
    if (j < HIDDEN) {
        acc = b[j];
        for (int k = 0; k < HIDDEN; k++)
            acc = fmaf(gemb[(size_t)g * HP + k], W[(size_t)k * HIDDEN + j], acc);
        acc = fmaxf(acc, 0.f);
    }
    gh[(size_t)g * HP + j] = (j < HIDDEN) ? acc : 0.f;
}
__global__ __launch_bounds__(64) void k_g2(const float* __restrict__ gh,
    const float* __restrict__ W, const float* __restrict__ b, float* __restrict__ out)
{
    int g = blockIdx.x, l = threadIdx.x;
    float acc = 0.f;
    for (int j = l; j < HIDDEN; j += 64) acc += gh[(size_t)g * HP + j] * W[j];
#pragma unroll
    for (int off = 32; off; off >>= 1) acc += __shfl_down(acc, off, 64);
    if (l == 0) out[g] = acc + b[0];
}

extern "C" void kernel_launch(void* const* d_in, const int* in_sizes, int n_in,
                              void* d_out, int out_size, void* d_ws, size_t ws_size,
                              hipStream_t stream)
{
    const float* f_atoms = (const float*)d_in[0];
    const float* f_bonds = (const float*)d_in[1];
    const int* a2b    = (const int*)d_in[2];
    const int* b2a    = (const int*)d_in[3];
    const int* gidx   = (const int*)d_in[5];
    const float* W_i    = (const float*)d_in[6];
    const float* W_h    = (const float*)d_in[7];
    const float* W_o    = (const float*)d_in[8];
    const float* b_o    = (const float*)d_in[9];
    const float* W_node = (const float*)d_in[10];
    const float* b_node = (const float*)d_in[11];
    const float* W_edge = (const float*)d_in[12];
    const float* b_edge = (const float*)d_in[13];
    const float* W_g1   = (const float*)d_in[14];
    const float* b_g1   = (const float*)d_in[15];
    const float* W_g2   = (const float*)d_in[16];
    const float* b_g2   = (const float*)d_in[17];

    char* ws = (char*)d_ws;
    u16* inp   = (u16*)(ws + 0);            // 128 MB (h1 pre-relu); later Ebuf
    u16* hA    = (u16*)(ws + 128000000);    // 128 MB: h2 -> h3
    u16* hB    = (u16*)(ws + 256000000);    // 128 MB: delta scratch -> ah
    u16* amsg  = (u16*)(ws + 384000000);    // 64 MB
    u16* wt_i  = (u16*)(ws + 448000000);    // 320x160
    u16* wt_h  = (u16*)(ws + 448200000);    // 320x320
    u16* wt_o  = (u16*)(ws + 448500000);    // 320x448
    u16* wt_ne = (u16*)(ws + 448800000);    // 320x320
    float* gemb = (float*)(ws + 449300000); // 2000x320 f32
    float* gh   = (float*)(ws + 452000000); // 2000x320 f32

    float* out_node  = (float*)d_out;
    float* out_edge  = out_node + (size_t)N_ATOMS * ATOM_FDIM;
    float* out_graph = out_node + 14700000;

    dim3 blk(256);

    // pack weights (bf16, transposed, zero-padded)
    k_pack_wt<<<(320 * 160 + 255) / 256, blk, 0, stream>>>(W_i, wt_i, BOND_FDIM, HIDDEN, 160, 320);
    k_pack_wt<<<(320 * 320 + 255) / 256, blk, 0, stream>>>(W_h, wt_h, HIDDEN, HIDDEN, 320, 320);
    k_pack_wo<<<(320 * CATP + 255) / 256, blk, 0, stream>>>(W_o, wt_o);
    k_pack_wne<<<(320 * 320 + 255) / 256, blk, 0, stream>>>(W_node, W_edge, wt_ne);

    const int mbB = (N_BONDS + 127) / 128;  // 1563
    const int mbA = (N_ATOMS + 127) / 128;  // 782
    const int gAg = (N_ATOMS * 40 + 255) / 256;
    const int gDl = (N_BONDS * 40 + 255) / 256;

    const int nwgI = 5 * mbB;   // W_i / W_h grids
    const int nwgO = 5 * mbA;   // W_o
    const int nwgH = 3 * mbA;   // merged head

    // inp = f_bonds @ W_i  (f32 staged in-kernel; pre-relu stored)
    k_gemmR<1, 1, 5, 5><<<nwgI, blk, 0, stream>>>(
        nullptr, f_bonds, N_BONDS, wt_i, 160, 0, nullptr, nullptr,
        inp, nullptr, nullptr, nullptr, nwgI);

    // depth loop: h' = inp + delta @ W_h; delta built by streaming kernel
    const u16* hcur = inp;
    for (int d = 0; d < 2; ++d) {
        k_aggregate<<<gAg, blk, 0, stream>>>(hcur, a2b, amsg);
        k_delta<<<gDl, blk, 0, stream>>>(amsg, hcur, b2a, hB);
        k_gemmR<0, 2, 10, 5><<<nwgI, blk, 0, stream>>>(
            hB, nullptr, N_BONDS, wt_h, 320, 0, nullptr, nullptr,
            hA, nullptr, nullptr, inp, nwgI);
        hcur = hA;
    }

    // final aggregate + fused-concat W_o -> atom_hiddens (relu'd, bf16) in hB
    k_aggregate<<<gAg, blk, 0, stream>>>(hcur, a2b, amsg);
    u16* ah = hB;   // delta scratch free
    k_gemmR<3, 3, 14, 5><<<nwgO, blk, 0, stream>>>(
        amsg, f_atoms, N_ATOMS, wt_o, CATP, HIDDEN, b_o, nullptr,
        ah, nullptr, nullptr, nullptr, nwgO);

    // merged node+edge head: cols 0..132 -> node preds, 133..146 -> E buffer
    float* Ebuf = (float*)inp;   // inp dead after last W_h gemm
    k_gemmR<0, 4, 10, 3><<<nwgH, blk, 0, stream>>>(
        ah, nullptr, N_ATOMS, wt_ne, 320, 0, b_node, b_edge,
        nullptr, out_node, Ebuf, nullptr, nwgH);

    // edge head finish: average endpoint E rows
    k_edge<<<(N_EDGES * 7 + 255) / 256, blk, 0, stream>>>(Ebuf, b2a, out_edge);

    // graph head
    k_segsum<<<N_MOLS, 320, 0, stream>>>(ah, gidx, gemb);
    k_g1<<<N_MOLS, 320, 0, stream>>>(gemb, W_g1, b_g1, gh);
    k_g2<<<N_MOLS, 64, 0, stream>>>(gh, W_g2, b_g2, out_graph);
}

// Round 14
// 1005.854 us; speedup vs baseline: 1.2050x; 1.1364x over previous
//
#include <hip/hip_runtime.h>

typedef unsigned short u16;
typedef unsigned int u32;

#define N_ATOMS 100000
#define N_BONDS 200000
#define N_EDGES 100000
#define HIDDEN 300
#define HP 320
#define ATOM_FDIM 133
#define BOND_FDIM 147
#define CATP 448
#define N_MOLS 2000

typedef __bf16 bf16x8 __attribute__((ext_vector_type(8)));
typedef float f32x4 __attribute__((ext_vector_type(4)));

__device__ __forceinline__ u16 f2bf(float f) {
    union { float f; u32 u; } x; x.f = f;
    u32 u = x.u;
    u32 r = u + 0x7fffu + ((u >> 16) & 1u);
    return (u16)(r >> 16);
}
__device__ __forceinline__ float bf2f(u16 h) {
    union { u32 u; float f; } x; x.u = ((u32)h) << 16;
    return x.f;
}

union U8 { uint4 v; u16 h[8]; };
union U4 { uint2 v; u16 h[4]; };

// async global->LDS, 16B per lane, LDS dest = base + lane*16 (HW-fixed)
#define GL16(gp, lp) __builtin_amdgcn_global_load_lds( \
    (const __attribute__((address_space(1))) u32*)(gp), \
    (__attribute__((address_space(3))) u32*)(lp), 16, 0, 0)

// ============ m97-style GEMM: 128x64 tile, global_load_lds staging ============
// 256 threads = 4 waves (2x2 wr/wc). Per k-step: each wave issues 2 A + 1 B
// global_load_lds (per-lane global addr, linear LDS [rows][32]), barrier
// (drains vmcnt), ds_read + 8 MFMA, barrier. A must be LINEAR bf16, stride LDA,
// K = KSTEPS*32 = LDA. N-fastest + bijective XCD swizzle for A-panel L2 reuse.
// Swapped-operand MFMA: lane holds 4 consecutive output cols.
// EP 1: O1=bf16(acc)                    (stride HP)
// EP 2: O1=bf16(acc + inp_in)          (inp pre-issued before k-loop)
// EP 3: O1=bf16(relu(acc + (col<Nout?bias:0)))
// EP 4: merged head via LDS-bounce: col<133 -> F1[row*133+col]=acc+bias[col];
//       133<=col<147 -> F2[row*16+col-133]=acc+bias2[col-133]
template<int EP, int KSTEPS, int LDA, int NB>
__global__ __launch_bounds__(256, 4) void k_gemmG(
    const u16* __restrict__ A, int M,
    const u16* __restrict__ Bt, int ldb, int Nout,
    const float* __restrict__ bias, const float* __restrict__ bias2,
    u16* __restrict__ O1, float* __restrict__ F1, float* __restrict__ F2,
    const u16* __restrict__ inp_in, int nwg)
{
    __shared__ __align__(16) u16 SM[128 * 32 + 64 * 32];   // A tile | B tile, linear
    u16* As = SM;
    u16* Bs = SM + 128 * 32;

    // bijective XCD-chunk swizzle (m204)
    const int bid = blockIdx.x;
    const int q = nwg >> 3, r = nwg & 7;
    const int xcd = bid & 7, sidx = bid >> 3;
    const int wg = (xcd < r ? xcd * (q + 1) : r * (q + 1) + (xcd - r) * q) + sidx;

    const int n0 = (wg % NB) * 64;
    const int row0 = (wg / NB) * 128;

    const int tid = threadIdx.x;
    const int lane = tid & 63;
    const int wv = tid >> 6;
    const int wr = wv >> 1, wc = wv & 1;
    const int lrow = lane & 15;
    const int g = lane >> 4;

    // staging lane map: instr covers 16 rows; lane l -> row +(l>>2), chunk l&3
    const int lr = lane >> 2, lc = lane & 3;
    int arow0 = row0 + wv * 32 + lr;
    int arow1 = arow0 + 16;
    if (arow0 >= M) arow0 = M - 1;
    if (arow1 >= M) arow1 = M - 1;
    const u16* gA0 = A + (size_t)arow0 * LDA + lc * 8;
    const u16* gA1 = A + (size_t)arow1 * LDA + lc * 8;
    const u16* gB  = Bt + (size_t)(n0 + wv * 16 + lr) * ldb + lc * 8;
    u16* lA0 = &As[(wv * 32) * 32];        // wave-uniform LDS bases
    u16* lA1 = &As[(wv * 32 + 16) * 32];
    u16* lB  = &Bs[(wv * 16) * 32];

    // EP2: pre-issue epilogue inp loads (complete long before epilogue)
    U4 ii[8];
    if constexpr (EP == 2) {
#pragma unroll
        for (int m = 0; m < 4; m++) {
            const int row = row0 + wr * 64 + m * 16 + lrow;
#pragma unroll
            for (int n = 0; n < 2; n++) {
                if (row < M)
                    ii[m * 2 + n].v = *(const uint2*)&inp_in[
                        (size_t)row * HP + n0 + wc * 32 + n * 16 + g * 4];
            }
        }
    }

    f32x4 acc[4][2] = {};

#pragma unroll
    for (int ks = 0; ks < KSTEPS; ks++) {
        const int k0 = ks * 32;
        GL16(gA0 + k0, lA0);
        GL16(gA1 + k0, lA1);
        GL16(gB + k0, lB);
        __syncthreads();
        bf16x8 af[4], bfr[2];
#pragma unroll
        for (int m = 0; m < 4; m++)
            af[m] = *(const bf16x8*)&As[(wr * 64 + m * 16 + lrow) * 32 + g * 8];
#pragma unroll
        for (int n = 0; n < 2; n++)
            bfr[n] = *(const bf16x8*)&Bs[(wc * 32 + n * 16 + lrow) * 32 + g * 8];
#pragma unroll
        for (int m = 0; m < 4; m++)
#pragma unroll
            for (int n = 0; n < 2; n++)
                acc[m][n] = __builtin_amdgcn_mfma_f32_16x16x32_bf16(bfr[n], af[m], acc[m][n], 0, 0, 0);
        __syncthreads();
    }

    if constexpr (EP == 4) {
        // LDS-bounce coalesced f32 epilogue: 32x64 slice per m, stride 68
        float* LDSf = (float*)SM;   // 32*68*4 = 8704 B <= 12288 B
#pragma unroll
        for (int m = 0; m < 4; m++) {
            __syncthreads();
#pragma unroll
            for (int n = 0; n < 2; n++)
                *(f32x4*)&LDSf[(size_t)(wr * 16 + lrow) * 68 + wc * 32 + n * 16 + g * 4] = acc[m][n];
            __syncthreads();
#pragma unroll
            for (int i = 0; i < 8; i++) {
                const int rl = wv + i * 4;                       // 0..31
                const int grow = row0 + ((rl & 16) ? 64 : 0) + m * 16 + (rl & 15);
                const float v = LDSf[(size_t)rl * 68 + lane];
                const int col = n0 + lane;                       // lane = column
                if (grow < M) {
                    if (col < 133) F1[(size_t)grow * 133 + col] = v + bias[col];
                    else if (col < 147) F2[(size_t)grow * 16 + (col - 133)] = v + bias2[col - 133];
                }
            }
        }
    } else {
#pragma unroll
        for (int m = 0; m < 4; m++) {
            const int row = row0 + wr * 64 + m * 16 + lrow;
            if (row >= M) continue;
#pragma unroll
            for (int n = 0; n < 2; n++) {
                const int colb = n0 + wc * 32 + n * 16 + g * 4;
                U4 o;
                if constexpr (EP == 1) {
#pragma unroll
                    for (int qq = 0; qq < 4; qq++) o.h[qq] = f2bf(acc[m][n][qq]);
                } else if constexpr (EP == 2) {
#pragma unroll
                    for (int qq = 0; qq < 4; qq++) o.h[qq] = f2bf(acc[m][n][qq] + bf2f(ii[m * 2 + n].h[qq]));
                } else {
#pragma unroll
                    for (int qq = 0; qq < 4; qq++) {
                        float x = acc[m][n][qq] + ((colb + qq) < Nout ? bias[colb + qq] : 0.f);
                        o.h[qq] = f2bf(fmaxf(x, 0.f));
                    }
                }
                *(uint2*)&O1[(size_t)row * HP + colb] = o.v;
            }
        }
    }
}

// ---------------- weight pack: Bt[n][k] = W[k][n], bf16, zero-padded ----------------
__global__ void k_pack_wt(const float* __restrict__ W, u16* __restrict__ Bt,
                          int K, int N, int Kp, int Np)
{
    int idx = blockIdx.x * 256 + threadIdx.x;
    if (idx >= Np * Kp) return;
    int n = idx / Kp, k = idx - n * Kp;
    Bt[idx] = (n < N && k < K) ? f2bf(W[(size_t)k * N + n]) : (u16)0;
}

// W_o pack with the [amsg(300) | pad4 | f_atoms(133) | pad] column reorder
__global__ void k_pack_wo(const float* __restrict__ W, u16* __restrict__ Bt)
{
    int idx = blockIdx.x * 256 + threadIdx.x;
    if (idx >= 320 * CATP) return;
    int n = idx / CATP, k = idx - n * CATP;
    float v = 0.f;
    if (n < HIDDEN) {
        if (k < HIDDEN) v = W[(size_t)(ATOM_FDIM + k) * HIDDEN + n];
        else if (k >= 304 && k < 304 + ATOM_FDIM) v = W[(size_t)(k - 304) * HIDDEN + n];
    }
    Bt[idx] = f2bf(v);
}

// merged head pack: Bt_ne[n][k]: n<133 from W_node, 133<=n<147 from W_edge
__global__ void k_pack_wne(const float* __restrict__ Wn, const float* __restrict__ We,
                           u16* __restrict__ Bt)
{
    int idx = blockIdx.x * 256 + threadIdx.x;
    if (idx >= 320 * 320) return;
    int n = idx / 320, k = idx - n * 320;
    float v = 0.f;
    if (k < HIDDEN) {
        if (n < ATOM_FDIM) v = Wn[(size_t)k * ATOM_FDIM + n];
        else if (n < ATOM_FDIM + 14) v = We[(size_t)k * 14 + (n - ATOM_FDIM)];
    }
    Bt[idx] = f2bf(v);
}

// ---------------- f_bonds fp32 [B][147] -> bf16 [B][160] ----------------
__global__ __launch_bounds__(256) void k_pack_bonds(const float* __restrict__ fb, u16* __restrict__ out)
{
    int idx = blockIdx.x * 256 + threadIdx.x;
    if (idx >= N_BONDS * 20) return;
    int b = idx / 20, c0 = (idx - b * 20) * 8;
    U8 u;
#pragma unroll
    for (int e = 0; e < 8; e++) {
        int col = c0 + e;
        u.h[e] = (col < BOND_FDIM) ? f2bf(fb[(size_t)b * BOND_FDIM + col]) : (u16)0;
    }
    *(uint4*)&out[(size_t)b * 160 + c0] = u.v;
}

// ---------------- fill catbuf cols 304..447 with bf16 f_atoms ----------------
__global__ __launch_bounds__(256) void k_cat_fa(const float* __restrict__ fa, u16* __restrict__ cat)
{
    int idx = blockIdx.x * 256 + threadIdx.x;
    if (idx >= N_ATOMS * 18) return;
    int a = idx / 18, c0 = 304 + (idx - a * 18) * 8;
    U8 u;
#pragma unroll
    for (int e = 0; e < 8; e++) {
        int fc = c0 + e - 304;
        u.h[e] = (fc < ATOM_FDIM) ? f2bf(fa[(size_t)a * ATOM_FDIM + fc]) : (u16)0;
    }
    *(uint4*)&cat[(size_t)a * CATP + c0] = u.v;
}

// ---------------- a_msg[a] = sum_j relu(h[a2b[a][j]]), output stride OST ----------------
template<int OST>
__global__ __launch_bounds__(256) void k_aggregate(const u16* __restrict__ h,
    const int* __restrict__ a2b, u16* __restrict__ amsg)
{
    int idx = blockIdx.x * 256 + threadIdx.x;
    if (idx >= N_ATOMS * 40) return;
    int a = idx / 40, c = (idx - a * 40) * 8;
    float s[8] = {};
#pragma unroll
    for (int j = 0; j < 6; j++) {
        int b = a2b[a * 6 + j];
        U8 u; u.v = *(const uint4*)&h[(size_t)b * HP + c];
#pragma unroll
        for (int i = 0; i < 8; i++) s[i] += fmaxf(bf2f(u.h[i]), 0.f);
    }
    U8 o;
#pragma unroll
    for (int i = 0; i < 8; i++) o.h[i] = f2bf(s[i]);
    *(uint4*)&amsg[(size_t)a * OST + c] = o.v;
}

// -------- delta[b] = amsg[b2a[b]] - relu(h[b^1])   (streaming, gathers here) --------
__global__ __launch_bounds__(256) void k_delta(const u16* __restrict__ amsg,
    const u16* __restrict__ h, const int* __restrict__ b2a, u16* __restrict__ dlt)
{
    int idx = blockIdx.x * 256 + threadIdx.x;
    if (idx >= N_BONDS * 40) return;
    int b = idx / 40, c = (idx - b * 40) * 8;
    int a = b2a[b];
    U8 x; x.v = *(const uint4*)&amsg[(size_t)a * HP + c];
    U8 y; y.v = *(const uint4*)&h[(size_t)(b ^ 1) * HP + c];
    U8 o;
#pragma unroll
    for (int i = 0; i < 8; i++)
        o.h[i] = f2bf(bf2f(x.h[i]) - fmaxf(bf2f(y.h[i]), 0.f));
    *(uint4*)&dlt[(size_t)b * HP + c] = o.v;
}

// -------- edge head finish: out[e] = 0.5*(E[b2a[2e]] + E[b2a[2e+1]]) --------
__global__ __launch_bounds__(256) void k_edge(const float* __restrict__ E,
    const int* __restrict__ b2a, float* __restrict__ out)
{
    int idx = blockIdx.x * 256 + threadIdx.x;
    if (idx >= N_EDGES * 7) return;
    int e = idx / 7, p = idx - e * 7;
    int a1 = b2a[2 * e], a2 = b2a[2 * e + 1];
    float2 x = *(const float2*)&E[(size_t)a1 * 16 + 2 * p];
    float2 y = *(const float2*)&E[(size_t)a2 * 16 + 2 * p];
    float2 o; o.x = 0.5f * (x.x + y.x); o.y = 0.5f * (x.y + y.y);
    *(float2*)&out[(size_t)e * 14 + 2 * p] = o;
}

// ---------------- per-molecule segment sum (graph_idx sorted) ----------------
__device__ __forceinline__ int lower_bound_i(const int* a, int n, int v) {
    int lo = 0, hi = n;
    while (lo < hi) { int mid = (lo + hi) >> 1; if (a[mid] < v) lo = mid + 1; else hi = mid; }
    return lo;
}
__global__ __launch_bounds__(320) void k_segsum(const u16* __restrict__ ah,
    const int* __restrict__ gidx, float* __restrict__ gemb)
{
    int g = blockIdx.x;
    int c = threadIdx.x;
    int s = lower_bound_i(gidx, N_ATOMS, g);
    int e = lower_bound_i(gidx, N_ATOMS, g + 1);
    float sum = 0.f;
    for (int a = s; a < e; a++) sum += bf2f(ah[(size_t)a * HP + c]);
    gemb[(size_t)g * HP + c] = sum;
}

// ---------------- graph head (fp32) ----------------
__global__ __launch_bounds__(320) void k_g1(const float* __restrict__ gemb,
    const float* __restrict__ W, const float* __restrict__ b, float* __restrict__ gh)
{
    int g = blockIdx.x, j = threadIdx.x;
    float acc = 0.f;
    if (j < HIDDEN) {
        acc = b[j];
        for (int k = 0; k < HIDDEN; k++)
            acc = fmaf(gemb[(size_t)g * HP + k], W[(size_t)k * HIDDEN + j], acc);
        acc = fmaxf(acc, 0.f);
    }
    gh[(size_t)g * HP + j] = (j < HIDDEN) ? acc : 0.f;
}
__global__ __launch_bounds__(64) void k_g2(const float* __restrict__ gh,
    const float* __restrict__ W, const float* __restrict__ b, float* __restrict__ out)
{
    int g = blockIdx.x, l = threadIdx.x;
    float acc = 0.f;
    for (int j = l; j < HIDDEN; j += 64) acc += gh[(size_t)g * HP + j] * W[j];
#pragma unroll
    for (int off = 32; off; off >>= 1) acc += __shfl_down(acc, off, 64);
    if (l == 0) out[g] = acc + b[0];
}

extern "C" void kernel_launch(void* const* d_in, const int* in_sizes, int n_in,
                              void* d_out, int out_size, void* d_ws, size_t ws_size,
                              hipStream_t stream)
{
    const float* f_atoms = (const float*)d_in[0];
    const float* f_bonds = (const float*)d_in[1];
    const int* a2b    = (const int*)d_in[2];
    const int* b2a    = (const int*)d_in[3];
    const int* gidx   = (const int*)d_in[5];
    const float* W_i    = (const float*)d_in[6];
    const float* W_h    = (const float*)d_in[7];
    const float* W_o    = (const float*)d_in[8];
    const float* b_o    = (const float*)d_in[9];
    const float* W_node = (const float*)d_in[10];
    const float* b_node = (const float*)d_in[11];
    const float* W_edge = (const float*)d_in[12];
    const float* b_edge = (const float*)d_in[13];
    const float* W_g1   = (const float*)d_in[14];
    const float* b_g1   = (const float*)d_in[15];
    const float* W_g2   = (const float*)d_in[16];
    const float* b_g2   = (const float*)d_in[17];

    char* ws = (char*)d_ws;
    u16* inp   = (u16*)(ws + 0);            // 128 MB: h1 pre-relu; later catbuf
    u16* hA    = (u16*)(ws + 128000000);    // 128 MB: fb16 pack -> h2/h3
    u16* hB    = (u16*)(ws + 256000000);    // 128 MB: delta scratch -> ah
    u16* amsg  = (u16*)(ws + 384000000);    // 64 MB: amsg -> Ebuf
    u16* wt_i  = (u16*)(ws + 448000000);    // 320x160
    u16* wt_h  = (u16*)(ws + 448200000);    // 320x320
    u16* wt_o  = (u16*)(ws + 448500000);    // 320x448
    u16* wt_ne = (u16*)(ws + 448800000);    // 320x320
    float* gemb = (float*)(ws + 449300000); // 2000x320 f32
    float* gh   = (float*)(ws + 452000000); // 2000x320 f32

    float* out_node  = (float*)d_out;
    float* out_edge  = out_node + (size_t)N_ATOMS * ATOM_FDIM;
    float* out_graph = out_node + 14700000;

    dim3 blk(256);

    // pack weights (bf16, transposed, zero-padded)
    k_pack_wt<<<(320 * 160 + 255) / 256, blk, 0, stream>>>(W_i, wt_i, BOND_FDIM, HIDDEN, 160, 320);
    k_pack_wt<<<(320 * 320 + 255) / 256, blk, 0, stream>>>(W_h, wt_h, HIDDEN, HIDDEN, 320, 320);
    k_pack_wo<<<(320 * CATP + 255) / 256, blk, 0, stream>>>(W_o, wt_o);
    k_pack_wne<<<(320 * 320 + 255) / 256, blk, 0, stream>>>(W_node, W_edge, wt_ne);

    const int mbB = (N_BONDS + 127) / 128;  // 1563
    const int mbA = (N_ATOMS + 127) / 128;  // 782
    const int gAg = (N_ATOMS * 40 + 255) / 256;
    const int gDl = (N_BONDS * 40 + 255) / 256;
    const int nwgI = 5 * mbB;
    const int nwgO = 5 * mbA;
    const int nwgH = 3 * mbA;

    // pack f_bonds -> bf16[200k][160] into hA (dead until depth-1 GEMM output)
    u16* fb16 = hA;
    k_pack_bonds<<<(N_BONDS * 20 + 255) / 256, blk, 0, stream>>>(f_bonds, fb16);

    // inp = f_bonds @ W_i  (pre-relu stored)
    k_gemmG<1, 5, 160, 5><<<nwgI, blk, 0, stream>>>(
        fb16, N_BONDS, wt_i, 160, 0, nullptr, nullptr,
        inp, nullptr, nullptr, nullptr, nwgI);

    // depth loop: h' = inp + delta @ W_h; delta built by streaming kernel
    const u16* hcur = inp;
    for (int d = 0; d < 2; ++d) {
        k_aggregate<HP><<<gAg, blk, 0, stream>>>(hcur, a2b, amsg);
        k_delta<<<gDl, blk, 0, stream>>>(amsg, hcur, b2a, hB);
        k_gemmG<2, 10, 320, 5><<<nwgI, blk, 0, stream>>>(
            hB, N_BONDS, wt_h, 320, 0, nullptr, nullptr,
            hA, nullptr, nullptr, inp, nwgI);
        hcur = hA;
    }

    // final aggregate -> catbuf (stride 448, cols 0..319; 300+ are zeros),
    // then fill cols 304..447 with bf16 f_atoms
    u16* catbuf = inp;   // inp dead after depth-2 GEMM
    k_aggregate<CATP><<<gAg, blk, 0, stream>>>(hcur, a2b, catbuf);
    k_cat_fa<<<(N_ATOMS * 18 + 255) / 256, blk, 0, stream>>>(f_atoms, catbuf);

    // atom_hiddens = relu(cat @ W_o + b_o) -> ah (bf16) in hB
    u16* ah = hB;
    k_gemmG<3, 14, 448, 5><<<nwgO, blk, 0, stream>>>(
        catbuf, N_ATOMS, wt_o, CATP, HIDDEN, b_o, nullptr,
        ah, nullptr, nullptr, nullptr, nwgO);

    // merged node+edge head: cols 0..132 -> node preds, 133..146 -> E buffer
    float* Ebuf = (float*)amsg;   // amsg dead after last k_delta
    k_gemmG<4, 10, 320, 3><<<nwgH, blk, 0, stream>>>(
        ah, N_ATOMS, wt_ne, 320, 0, b_node, b_edge,
        nullptr, out_node, Ebuf, nwgH ? nullptr : nullptr, nwgH);

    // edge head finish: average endpoint E rows
    k_edge<<<(N_EDGES * 7 + 255) / 256, blk, 0, stream>>>(Ebuf, b2a, out_edge);

    // graph head
    k_segsum<<<N_MOLS, 320, 0, stream>>>(ah, gidx, gemb);
    k_g1<<<N_MOLS, 320, 0, stream>>>(gemb, W_g1, b_g1, gh);
    k_g2<<<N_MOLS, 64, 0, stream>>>(gh, W_g2, b_g2, out_graph);
}